// Round 10
// baseline (2859.806 us; speedup 1.0000x reference)
//
#include <hip/hip_runtime.h>
#include <hip/hip_bf16.h>

// BitNet-style ternary MLP: out = relu(x @ Wfc_q^T * s_fc)^2 @ Wproj_q^T * s_proj
// B=8 S=4096 D=2048 H=5120 -> M=32768.
// GEMMs: 256x256 tile, BK=64, 8 waves (2x4, 128x64/wave), 16x16x32 MFMA.
// KEY CHANGE (r10): B (ternary weights) is NOT staged in LDS — B-fragments are
// loaded global->VGPR (L2-resident via bm-fastest grid order), double-buffered
// in registers one tile ahead. LDS holds A only: 3 x 32KB rotating buffers,
// 1 barrier/tile, counted vmcnt(12) gate. This cuts LDS-pipe work ~45% so the
// MFMA pipe (2480 cyc/tile/SIMD floor) dominates. T2 swizzle on A (proven
// 0-conflict); T5 setprio; T1 bijective XCD swizzle.

typedef __attribute__((ext_vector_type(8))) short short8;
typedef __attribute__((ext_vector_type(4))) float f32x4;

#define BM 256
#define BN 256
#define BK 64
#define ABUF 16384  // elems (shorts) per A buffer: A[256][64] = 32 KiB

__device__ __forceinline__ unsigned short f2bf(float f) {
  unsigned int u = __float_as_uint(f);
  u += 0x7FFFu + ((u >> 16) & 1u);  // RNE
  return (unsigned short)(u >> 16);
}

__device__ __forceinline__ void gload_lds16(const void* gsrc, void* ldst) {
  __builtin_amdgcn_global_load_lds(
      (const __attribute__((address_space(1))) unsigned int*)gsrc,
      (__attribute__((address_space(3))) unsigned int*)ldst, 16, 0, 0);
}

// ---------- pass 1: |w| sum partials (deterministic, fp64 accumulate) ----------
__global__ void k_reduce_abs(const float4* __restrict__ w, int n4,
                             double* __restrict__ partial) {
  __shared__ double sm[256];
  double s = 0.0;
  const int stride = gridDim.x * blockDim.x;
  for (int i = blockIdx.x * blockDim.x + threadIdx.x; i < n4; i += stride) {
    float4 v = w[i];
    s += (double)fabsf(v.x);
    s += (double)fabsf(v.y);
    s += (double)fabsf(v.z);
    s += (double)fabsf(v.w);
  }
  sm[threadIdx.x] = s;
  __syncthreads();
  for (int off = 128; off > 0; off >>= 1) {
    if (threadIdx.x < off) sm[threadIdx.x] += sm[threadIdx.x + off];
    __syncthreads();
  }
  if (threadIdx.x == 0) partial[blockIdx.x] = sm[0];
}

// ---------- pass 2: finalize abs_mean / thr for both weights ----------
__global__ void k_finalize(const double* __restrict__ partial,
                           float* __restrict__ scales, double inv_n) {
  __shared__ double sm[256];
  const int t = threadIdx.x;
  for (int seg = 0; seg < 2; ++seg) {
    const double* p = partial + seg * 1024;
    double s = p[t * 4] + p[t * 4 + 1] + p[t * 4 + 2] + p[t * 4 + 3];
    sm[t] = s;
    __syncthreads();
    for (int off = 128; off > 0; off >>= 1) {
      if (t < off) sm[t] += sm[t + off];
      __syncthreads();
    }
    if (t == 0) {
      float am = (float)(sm[0] * inv_n);
      am = fmaxf(am, 1e-5f);
      scales[seg * 2] = am;             // abs_mean
      scales[seg * 2 + 1] = 0.7f * am;  // threshold
    }
    __syncthreads();
  }
}

// ---------- ternarize: fp32 w -> bf16 q in {-1,0,+1} ----------
__global__ void k_ternarize(const float4* __restrict__ w, ushort4* __restrict__ q,
                            const float* __restrict__ scales, int sidx, int n4) {
  const float thr = scales[sidx * 2 + 1];
  const int stride = gridDim.x * blockDim.x;
  for (int i = blockIdx.x * blockDim.x + threadIdx.x; i < n4; i += stride) {
    float4 v = w[i];
    ushort4 o;
    o.x = v.x > thr ? 0x3F80u : (v.x < -thr ? 0xBF80u : 0u);
    o.y = v.y > thr ? 0x3F80u : (v.y < -thr ? 0xBF80u : 0u);
    o.z = v.z > thr ? 0x3F80u : (v.z < -thr ? 0xBF80u : 0u);
    o.w = v.w > thr ? 0x3F80u : (v.w < -thr ? 0xBF80u : 0u);
    q[i] = o;
  }
}

// ---------- x: fp32 -> bf16 ----------
__global__ void k_f32_to_bf16(const float4* __restrict__ x, ushort4* __restrict__ o,
                              int n4) {
  const int stride = gridDim.x * blockDim.x;
  for (int i = blockIdx.x * blockDim.x + threadIdx.x; i < n4; i += stride) {
    float4 v = x[i];
    ushort4 r;
    r.x = f2bf(v.x);
    r.y = f2bf(v.y);
    r.z = f2bf(v.z);
    r.w = f2bf(v.w);
    o[i] = r;
  }
}

// ======= 256x256 8-wave GEMM: A via LDS (3-buf), B direct global->VGPR =======
// C = A * B^T. A[M][K], B[N][K] bf16; fp32 acc.
// A buffer i at elem offset i*ABUF. Swizzle: LDS[row][c8] = G[row][c8 ^ (row&7)]
// (8-elem chunks); frag reads XOR the same (proven 0-conflict).
// Per K-tile: load B(T+1)->regs (8 gl_dwordx4), stage A(T+2)->freed buf
// (4 gload_lds), 16 ds_read_b128 (2 quadrants), 64 MFMA, vmcnt(12), s_barrier.

#define ST1A(bufo, r0, k0)                         \
  gload_lds16(Ast + (size_t)(r0) * K + (k0),       \
              (void*)(lptr + (bufo) + (r0) * 64))

#define ST_A4(bufo, k0)            \
  do {                             \
    ST1A((bufo), w8, k0);          \
    ST1A((bufo), 64 + w8, k0);     \
    ST1A((bufo), 128 + w8, k0);    \
    ST1A((bufo), 192 + w8, k0);    \
  } while (0)

// 8 x ds_read_b128 : A quadrant (64 rows) fragments for K=64
#define LDA(p_, qr)                                                            \
  do {                                                                         \
    const unsigned short* ab =                                                 \
        lptr + (p_) + (wr * 128 + (qr) * 64 + fr) * 64;                        \
    _Pragma("unroll") for (int ri = 0; ri < 4; ++ri) {                         \
      af[ri][0] = *(const short8*)(ab + ri * 1024 + csw0);                     \
      af[ri][1] = *(const short8*)(ab + ri * 1024 + csw1);                     \
    }                                                                          \
  } while (0)

// 8 x global_load_dwordx4 : full B fragment set (64 cols x K=64) for tile kt
#define LOADB(dst, kt)                                                         \
  do {                                                                         \
    const unsigned short* bgp = Bfrag + (size_t)(kt) * BK;                     \
    _Pragma("unroll") for (int ci = 0; ci < 4; ++ci)                           \
    _Pragma("unroll") for (int kk = 0; kk < 2; ++kk)                           \
      dst[ci][kk] = *(const short8*)(bgp + (size_t)ci * 16 * K + kk * 32);     \
  } while (0)

#define MFMA32(bqv, qr)                                                        \
  do {                                                                         \
    __builtin_amdgcn_s_setprio(1);                                             \
    _Pragma("unroll") for (int kk = 0; kk < 2; ++kk)                           \
    _Pragma("unroll") for (int ri = 0; ri < 4; ++ri)                           \
    _Pragma("unroll") for (int ci = 0; ci < 4; ++ci)                           \
      acc[(qr) * 4 + ri][ci] = __builtin_amdgcn_mfma_f32_16x16x32_bf16(        \
          af[ri][kk], bqv[ci][kk], acc[(qr) * 4 + ri][ci], 0, 0, 0);           \
    __builtin_amdgcn_s_setprio(0);                                             \
  } while (0)

#define BAR()                           \
  do {                                  \
    asm volatile("" ::: "memory");      \
    __builtin_amdgcn_s_barrier();       \
    asm volatile("" ::: "memory");      \
  } while (0)

#define GATE(Tcur)                                                  \
  do {                                                              \
    if ((Tcur) + 2 < nk) {                                          \
      asm volatile("s_waitcnt vmcnt(12)" ::: "memory");             \
    } else if ((Tcur) + 1 < nk) {                                   \
      asm volatile("s_waitcnt vmcnt(8)" ::: "memory");              \
    }                                                               \
    BAR();                                                          \
  } while (0)

template <int EPI>
__global__ __launch_bounds__(512, 2) void k_gemm_bt(
    const unsigned short* __restrict__ A, const unsigned short* __restrict__ B,
    void* __restrict__ Cout, int M, int N, int K,
    const float* __restrict__ scales, int sidx, int nbm) {
  __shared__ __align__(16) unsigned short lds[3 * ABUF];  // 96 KiB (A only)
  unsigned short* lptr = lds;

  const int tid = threadIdx.x;
  const int lane = tid & 63;
  const int w = tid >> 6;   // wave 0..7
  const int wr = w >> 2;    // 0..1 -> 128 rows
  const int wc = w & 3;     // 0..3 -> 64 cols

  // T1: bijective XCD swizzle; bm-FASTEST order so an XCD chunk shares few
  // bn values -> B panels stay L2-resident
  const int nwg = gridDim.x;
  const int cpx = nwg >> 3;
  const int bid = blockIdx.x;
  const int swz = (bid & 7) * cpx + (bid >> 3);
  const int bm = swz % nbm;
  const int bn = swz / nbm;
  const int rowA0 = bm * BM;
  const int rowB0 = bn * BN;

  // A staging lane geometry (proven swizzle): 8 rows/instr
  const int srow = lane >> 3;
  const int scol = ((lane & 7) ^ srow) << 3;  // bf16 elems
  const unsigned short* Ast = A + (size_t)(rowA0 + srow) * K + scol;

  // frag-read lane geometry
  const int fr = lane & 15;
  const int kgrp = lane >> 4;
  const int csw0 = (kgrp << 3) ^ ((fr & 7) << 3);
  const int csw1 = (32 + (kgrp << 3)) ^ ((fr & 7) << 3);
  const int w8 = w << 3;

  // B direct-global per-lane base: row = rowB0 + wc*64 + fr, k-chunk = kgrp*8
  const unsigned short* Bfrag =
      B + ((size_t)rowB0 + wc * 64 + fr) * K + (kgrp << 3);

  f32x4 acc[8][4];
#pragma unroll
  for (int i = 0; i < 8; ++i)
#pragma unroll
    for (int j = 0; j < 4; ++j) acc[i][j] = (f32x4){0.f, 0.f, 0.f, 0.f};

  short8 af[4][2], bqA[4][2], bqB[4][2];

  const int nk = K / BK;  // even (32 or 80)

  // prologue: B(0)->bqA; stage A(0)->buf0, A(1)->buf1; force B(0)+A(0)
  LOADB(bqA, 0);
  ST_A4(0, 0);
  if (nk > 1) {
    ST_A4(ABUF, BK);
    asm volatile("s_waitcnt vmcnt(4)" ::: "memory");
  } else {
    asm volatile("s_waitcnt vmcnt(0)" ::: "memory");
  }
  BAR();

  int cur = 0, nxt = ABUF, stg = 2 * ABUF;
  for (int T = 0; T < nk; T += 2) {
    // ---- sub-tile T: use bqA, prefetch bqB(T+1) ----
    LOADB(bqB, T + 1);                       // T+1 <= nk-1 always (nk even)
    if (T + 2 < nk) ST_A4(stg, (T + 2) * BK);
    LDA(cur, 0);
    MFMA32(bqA, 0);
    LDA(cur, 1);
    MFMA32(bqA, 1);
    GATE(T);
    { const int t = cur; cur = nxt; nxt = stg; stg = t; }

    // ---- sub-tile T+1: use bqB, prefetch bqA(T+2) ----
    if (T + 2 < nk) LOADB(bqA, T + 2);
    if (T + 3 < nk) ST_A4(stg, (T + 3) * BK);
    LDA(cur, 0);
    MFMA32(bqB, 0);
    LDA(cur, 1);
    MFMA32(bqB, 1);
    GATE(T + 1);
    { const int t = cur; cur = nxt; nxt = stg; stg = t; }
  }

  // epilogue: C/D layout col = lane&15, row = (lane>>4)*4 + q
  const float s = scales[sidx * 2];
  const int crow0 = rowA0 + wr * 128 + (lane >> 4) * 4;
  const int ccol0 = rowB0 + wc * 64 + (lane & 15);
  if (EPI == 0) {
    const float s2 = s * s;
    unsigned short* C = (unsigned short*)Cout;
#pragma unroll
    for (int ri = 0; ri < 8; ++ri)
#pragma unroll
      for (int ci = 0; ci < 4; ++ci)
#pragma unroll
        for (int q = 0; q < 4; ++q) {
          float v = acc[ri][ci][q];
          v = fmaxf(v, 0.0f);
          v = v * v * s2;
          C[(size_t)(crow0 + ri * 16 + q) * N + (ccol0 + ci * 16)] = f2bf(v);
        }
  } else {
    float* C = (float*)Cout;
#pragma unroll
    for (int ri = 0; ri < 8; ++ri)
#pragma unroll
      for (int ci = 0; ci < 4; ++ci)
#pragma unroll
        for (int q = 0; q < 4; ++q)
          C[(size_t)(crow0 + ri * 16 + q) * N + (ccol0 + ci * 16)] =
              acc[ri][ci][q] * s;
  }
}

extern "C" void kernel_launch(void* const* d_in, const int* in_sizes, int n_in,
                              void* d_out, int out_size, void* d_ws, size_t ws_size,
                              hipStream_t stream) {
  const int Mdim = 32768;  // B*S
  const int Ddim = 2048;
  const int Hdim = 5120;
  const int NW = Hdim * Ddim;  // elements per weight

  const float* x = (const float*)d_in[0];
  const float* w_fc = (const float*)d_in[1];
  const float* w_proj = (const float*)d_in[2];
  float* out = (float*)d_out;

  char* ws = (char*)d_ws;
  double* partial = (double*)ws;                          // 16 KB
  float* scales = (float*)(ws + 16384);                   // 4 floats
  unsigned short* wq_fc = (unsigned short*)(ws + 32768);  // 20 MB
  unsigned short* wq_proj = wq_fc + (size_t)NW;           // 20 MB
  unsigned short* xbf = wq_proj + (size_t)NW;             // 128 MB
  unsigned short* hbf = xbf + (size_t)Mdim * Ddim;        // 320 MB

  // 1) abs-mean reductions (deterministic, fp64)
  k_reduce_abs<<<1024, 256, 0, stream>>>((const float4*)w_fc, NW / 4, partial);
  k_reduce_abs<<<1024, 256, 0, stream>>>((const float4*)w_proj, NW / 4,
                                         partial + 1024);
  k_finalize<<<1, 256, 0, stream>>>(partial, scales, 1.0 / (double)NW);

  // 2) ternarize weights -> bf16 q
  k_ternarize<<<2048, 256, 0, stream>>>((const float4*)w_fc, (ushort4*)wq_fc,
                                        scales, 0, NW / 4);
  k_ternarize<<<2048, 256, 0, stream>>>((const float4*)w_proj, (ushort4*)wq_proj,
                                        scales, 1, NW / 4);

  // 3) x -> bf16
  k_f32_to_bf16<<<2048, 256, 0, stream>>>((const float4*)x, (ushort4*)xbf,
                                          (Mdim * Ddim) / 4);

  // 4) h = relu(x @ Wfc^T * s)^2  [M x H] bf16
  k_gemm_bt<0><<<dim3((Hdim / BN) * (Mdim / BM)), 512, 0, stream>>>(
      xbf, wq_fc, hbf, Mdim, Hdim, Ddim, scales, 0, Mdim / BM);

  // 5) out = h @ Wproj^T * s  [M x D] fp32
  k_gemm_bt<1><<<dim3((Ddim / BN) * (Mdim / BM)), 512, 0, stream>>>(
      hbf, wq_proj, out, Mdim, Ddim, Hdim, scales, 1, Mdim / BM);
}